// Round 1
// baseline (839.074 us; speedup 1.0000x reference)
//
#include <hip/hip_runtime.h>
#include <cstddef>

namespace {

constexpr int kN = 32;
constexpr int kC = 512;
constexpr int kHW = 3136;   // 56*56
constexpr int kL = 64;
constexpr int kCT = 512;
constexpr int kTok = 561;   // CT + 49
constexpr int kKcat = 576;  // 561 padded to 18*32

// ---------------- weight prep ----------------
// w_eff[d, g*32+k] = sum_{d'} w_tok[d, g*32+d'] * w_val[g, d', k]; cols 512..560 = w_tok tail; 561..575 = 0
__global__ __launch_bounds__(256) void build_wcat_kernel(
    const float* __restrict__ w_tok, const float* __restrict__ w_val,
    float* __restrict__ wcat) {
  int idx = blockIdx.x * 256 + threadIdx.x;
  if (idx >= kCT * kKcat) return;
  int d = idx / kKcat;
  int c = idx - d * kKcat;
  float v = 0.f;
  if (c < kCT) {
    int g = c >> 5, k = c & 31;
    const float* wt = w_tok + (size_t)d * kTok + g * 32;
    const float* wv = w_val + g * 1024 + k;
    float s = 0.f;
#pragma unroll
    for (int dp = 0; dp < 32; ++dp) s += wt[dp] * wv[dp * 32];
    v = s;
  } else if (c < kTok) {
    v = w_tok[(size_t)d * kTok + c];
  }
  wcat[idx] = v;
}

// cst[d] = b_tok[d] + sum_c w_tok[d,c]*b_val[c]   (uses sum_p softmax = 1)
__global__ __launch_bounds__(256) void build_cst_kernel(
    const float* __restrict__ w_tok, const float* __restrict__ b_val,
    const float* __restrict__ b_tok, float* __restrict__ cst) {
  int d = blockIdx.x * 256 + threadIdx.x;
  if (d >= kCT) return;
  float s = b_tok[d];
  for (int c = 0; c < kCT; ++c) s += w_tok[(size_t)d * kTok + c] * b_val[c];
  cst[d] = s;
}

__global__ __launch_bounds__(256) void zero_pad_kernel(float* __restrict__ bcat) {
  int i = blockIdx.x * 256 + threadIdx.x;
  const int tot = kN * (kKcat - kTok) * kL;
  if (i >= tot) return;
  int n = i / ((kKcat - kTok) * kL);
  int r = i - n * ((kKcat - kTok) * kL);
  bcat[(size_t)n * kKcat * kL + (size_t)kTok * kL + r] = 0.f;
}

// ---------------- K1: tc_raw[n][p][l] = (w_tc @ feature[n] + b_tc)/sqrt(C) ----------------
// block: (p-chunk 64) x (n); 64 threads; 64(l) x 64(p) tile; thread tile 8x8
__global__ __launch_bounds__(64) void tc_gemm_kernel(
    const float* __restrict__ feat, const float* __restrict__ w_tc,
    const float* __restrict__ b_tc, float* __restrict__ tc) {
  const int n = blockIdx.y;
  const int p0 = blockIdx.x * 64;
  const int tid = threadIdx.x;
  __shared__ float fs[32][64];   // [k][p]
  __shared__ float wsh[32][64];  // [k][l]
  const int tp = tid & 7;
  const int tl = tid >> 3;
  float acc[8][8];  // [l][p]
#pragma unroll
  for (int i = 0; i < 8; ++i)
#pragma unroll
    for (int j = 0; j < 8; ++j) acc[i][j] = 0.f;

  const float* fbase = feat + (size_t)n * kC * kHW + p0;
  const int col4 = (tid & 15) * 4;
  const int krow = tid >> 4;

  for (int c0 = 0; c0 < kC; c0 += 32) {
#pragma unroll
    for (int r = 0; r < 8; ++r) {
      int k = krow + r * 4;
      *(float4*)&fs[k][col4] =
          *(const float4*)(fbase + (size_t)(c0 + k) * kHW + col4);
    }
    const float* wrow = w_tc + (size_t)tid * kC + c0;
#pragma unroll
    for (int r = 0; r < 8; ++r) {
      float4 v = *(const float4*)(wrow + r * 4);
      wsh[r * 4 + 0][tid] = v.x;
      wsh[r * 4 + 1][tid] = v.y;
      wsh[r * 4 + 2][tid] = v.z;
      wsh[r * 4 + 3][tid] = v.w;
    }
    __syncthreads();
#pragma unroll 8
    for (int k = 0; k < 32; ++k) {
      float4 a0 = *(const float4*)&fs[k][tp * 8];
      float4 a1 = *(const float4*)&fs[k][tp * 8 + 4];
      float4 w0 = *(const float4*)&wsh[k][tl * 8];
      float4 w1 = *(const float4*)&wsh[k][tl * 8 + 4];
      float av[8] = {a0.x, a0.y, a0.z, a0.w, a1.x, a1.y, a1.z, a1.w};
      float wv[8] = {w0.x, w0.y, w0.z, w0.w, w1.x, w1.y, w1.z, w1.w};
#pragma unroll
      for (int i = 0; i < 8; ++i)
#pragma unroll
        for (int j = 0; j < 8; ++j) acc[i][j] += wv[i] * av[j];
    }
    __syncthreads();
  }
  const float inv = 0.04419417382415922f;  // 1/sqrt(512)
  float bt[8];
#pragma unroll
  for (int i = 0; i < 8; ++i) bt[i] = b_tc[tl * 8 + i];
  float* obase = tc + (size_t)n * kHW * kL + (size_t)(p0 + tp * 8) * kL + tl * 8;
#pragma unroll
  for (int j = 0; j < 8; ++j) {
    float4 u, v;
    u.x = (acc[0][j] + bt[0]) * inv;
    u.y = (acc[1][j] + bt[1]) * inv;
    u.z = (acc[2][j] + bt[2]) * inv;
    u.w = (acc[3][j] + bt[3]) * inv;
    v.x = (acc[4][j] + bt[4]) * inv;
    v.y = (acc[5][j] + bt[5]) * inv;
    v.z = (acc[6][j] + bt[6]) * inv;
    v.w = (acc[7][j] + bt[7]) * inv;
    *(float4*)(obase + (size_t)j * kL) = u;
    *(float4*)(obase + (size_t)j * kL + 4) = v;
  }
}

// ---------------- K2: softmax over p (HW) per (n,l), in place ----------------
__global__ __launch_bounds__(256) void softmax_kernel(float* __restrict__ tc) {
  const int n = blockIdx.x;
  const int l = threadIdx.x & 63;
  const int s = threadIdx.x >> 6;  // 4 slices
  float* base = tc + (size_t)n * kHW * kL + l;
  const int P = kHW / 4;  // 784
  const int p0 = s * P;
  __shared__ float red[4][64];
  float m = -3.0e38f;
  for (int i = 0; i < P; ++i) m = fmaxf(m, base[(size_t)(p0 + i) * kL]);
  red[s][l] = m;
  __syncthreads();
  m = fmaxf(fmaxf(red[0][l], red[1][l]), fmaxf(red[2][l], red[3][l]));
  float sum = 0.f;
  for (int i = 0; i < P; ++i) sum += expf(base[(size_t)(p0 + i) * kL] - m);
  __syncthreads();
  red[s][l] = sum;
  __syncthreads();
  sum = red[0][l] + red[1][l] + red[2][l] + red[3][l];
  const float invs = 1.f / sum;
  for (int i = 0; i < P; ++i) {
    size_t off = (size_t)(p0 + i) * kL;
    base[off] = expf(base[off] - m) * invs;
  }
}

// ---------------- K3: partial[s][n][c][l] = feature[n][c][k0:k1] @ tc[n][k0:k1][l] ----------------
__global__ __launch_bounds__(64) void m_gemm_kernel(
    const float* __restrict__ feat, const float* __restrict__ tc,
    float* __restrict__ part, int klen) {
  const int cb = blockIdx.x * 64;
  const int n = blockIdx.y;
  const int s = blockIdx.z;
  const int k0 = s * klen;
  const int tid = threadIdx.x;
  __shared__ float ash[32][64];  // [k][c]
  __shared__ float bsh[32][64];  // [k][l]
  const int ti = tid >> 3;  // c
  const int tj = tid & 7;   // l
  float acc[8][8];
#pragma unroll
  for (int i = 0; i < 8; ++i)
#pragma unroll
    for (int j = 0; j < 8; ++j) acc[i][j] = 0.f;

  const float* fbase = feat + (size_t)n * kC * kHW + (size_t)cb * kHW + k0;
  const float* bbase = tc + (size_t)n * kHW * kL + (size_t)k0 * kL;
  const int col4 = (tid & 15) * 4;
  const int krow = tid >> 4;

  for (int kk = 0; kk < klen; kk += 32) {
    const float* frow = fbase + (size_t)tid * kHW + kk;
#pragma unroll
    for (int r = 0; r < 8; ++r) {
      float4 v = *(const float4*)(frow + r * 4);
      ash[r * 4 + 0][tid] = v.x;
      ash[r * 4 + 1][tid] = v.y;
      ash[r * 4 + 2][tid] = v.z;
      ash[r * 4 + 3][tid] = v.w;
    }
#pragma unroll
    for (int r = 0; r < 8; ++r) {
      int k = krow + r * 4;
      *(float4*)&bsh[k][col4] =
          *(const float4*)(bbase + (size_t)(kk + k) * kL + col4);
    }
    __syncthreads();
#pragma unroll 8
    for (int k = 0; k < 32; ++k) {
      float4 a0 = *(const float4*)&ash[k][ti * 8];
      float4 a1 = *(const float4*)&ash[k][ti * 8 + 4];
      float4 b0 = *(const float4*)&bsh[k][tj * 8];
      float4 b1 = *(const float4*)&bsh[k][tj * 8 + 4];
      float av[8] = {a0.x, a0.y, a0.z, a0.w, a1.x, a1.y, a1.z, a1.w};
      float bv[8] = {b0.x, b0.y, b0.z, b0.w, b1.x, b1.y, b1.z, b1.w};
#pragma unroll
      for (int i = 0; i < 8; ++i)
#pragma unroll
        for (int j = 0; j < 8; ++j) acc[i][j] += av[i] * bv[j];
    }
    __syncthreads();
  }
  float* obase = part + ((size_t)s * kN + n) * kCT * kL +
                 (size_t)(cb + ti * 8) * kL + tj * 8;
#pragma unroll
  for (int i = 0; i < 8; ++i) {
    float4 u = {acc[i][0], acc[i][1], acc[i][2], acc[i][3]};
    float4 v = {acc[i][4], acc[i][5], acc[i][6], acc[i][7]};
    *(float4*)(obase + (size_t)i * kL) = u;
    *(float4*)(obase + (size_t)i * kL + 4) = v;
  }
}

__global__ __launch_bounds__(256) void reduce_m_kernel(
    const float* __restrict__ part, float* __restrict__ bcat, int ksplit) {
  int i = blockIdx.x * 256 + threadIdx.x;
  if (i >= kN * kCT * kL) return;
  int n = i >> 15;
  int r = i & 32767;
  float s = 0.f;
  for (int ss = 0; ss < ksplit; ++ss)
    s += part[(size_t)ss * kN * kCT * kL + i];
  bcat[(size_t)n * kKcat * kL + r] = s;
}

// ---------------- K4: PosEncoder -> bcat rows 512..560 ----------------
__global__ __launch_bounds__(64) void pos_enc_kernel(
    const float* __restrict__ tc, const float* __restrict__ w3,
    const float* __restrict__ b3, const float* __restrict__ w1,
    const float* __restrict__ b1, const float* __restrict__ wp,
    const float* __restrict__ bp, float* __restrict__ bcat) {
  const int n = blockIdx.x;
  const int l = threadIdx.x;  // 64 threads = token index l'
  __shared__ float pcl[64][49];
  const float* base = tc + (size_t)(n * 64 + l) * kHW;  // .view reinterpretation
  float w3r[9];
#pragma unroll
  for (int i = 0; i < 9; ++i) w3r[i] = w3[i];
  const float s1 = w1[0], sb3 = b3[0], sb1 = b1[0];
#pragma unroll
  for (int y = 0; y < 7; ++y) {
#pragma unroll
    for (int x = 0; x < 7; ++x) {
      float a = 0.f;
#pragma unroll
      for (int dy = 0; dy < 3; ++dy) {
        int i = 2 * y - 1 + dy;
        if (i < 0 || i >= 14) continue;
#pragma unroll
        for (int dx = 0; dx < 3; ++dx) {
          int j = 2 * x - 1 + dx;
          if (j < 0 || j >= 14) continue;
          // nearest-resized 14x14 pixel (i,j) = tc_flat[m*3136 + 4i*56 + 4j]
          a += w3r[dy * 3 + dx] * base[224 * i + 4 * j];
        }
      }
      pcl[l][y * 7 + x] = (a + sb3) * s1 + sb1;
    }
  }
  __syncthreads();
  for (int d = 0; d < 49; ++d) {
    float s = bp[d];
#pragma unroll
    for (int q = 0; q < 49; ++q) s += wp[d * 49 + q] * pcl[l][q];
    bcat[(size_t)n * kKcat * kL + (size_t)(kCT + d) * kL + l] = s;
  }
}

// ---------------- K5: out[n][d][l] = cst[d] + wcat[d,:] @ bcat[n][:,l] ----------------
__global__ __launch_bounds__(64) void out_gemm_kernel(
    const float* __restrict__ wcat, const float* __restrict__ bcat,
    const float* __restrict__ cst, float* __restrict__ out) {
  const int db = blockIdx.x * 64;
  const int n = blockIdx.y;
  const int tid = threadIdx.x;
  __shared__ float ash[32][64];  // [k][d]
  __shared__ float bsh[32][64];  // [k][l]
  const int ti = tid >> 3;  // d
  const int tj = tid & 7;   // l
  float acc[8][8];
#pragma unroll
  for (int i = 0; i < 8; ++i)
#pragma unroll
    for (int j = 0; j < 8; ++j) acc[i][j] = 0.f;

  const float* arow = wcat + (size_t)(db + tid) * kKcat;
  const float* bbase = bcat + (size_t)n * kKcat * kL;
  const int col4 = (tid & 15) * 4;
  const int krow = tid >> 4;

  for (int c0 = 0; c0 < kKcat; c0 += 32) {
#pragma unroll
    for (int r = 0; r < 8; ++r) {
      float4 v = *(const float4*)(arow + c0 + r * 4);
      ash[r * 4 + 0][tid] = v.x;
      ash[r * 4 + 1][tid] = v.y;
      ash[r * 4 + 2][tid] = v.z;
      ash[r * 4 + 3][tid] = v.w;
    }
#pragma unroll
    for (int r = 0; r < 8; ++r) {
      int k = krow + r * 4;
      *(float4*)&bsh[k][col4] =
          *(const float4*)(bbase + (size_t)(c0 + k) * kL + col4);
    }
    __syncthreads();
#pragma unroll 8
    for (int k = 0; k < 32; ++k) {
      float4 a0 = *(const float4*)&ash[k][ti * 8];
      float4 a1 = *(const float4*)&ash[k][ti * 8 + 4];
      float4 b0 = *(const float4*)&bsh[k][tj * 8];
      float4 b1 = *(const float4*)&bsh[k][tj * 8 + 4];
      float av[8] = {a0.x, a0.y, a0.z, a0.w, a1.x, a1.y, a1.z, a1.w};
      float bv[8] = {b0.x, b0.y, b0.z, b0.w, b1.x, b1.y, b1.z, b1.w};
#pragma unroll
      for (int i = 0; i < 8; ++i)
#pragma unroll
        for (int j = 0; j < 8; ++j) acc[i][j] += av[i] * bv[j];
    }
    __syncthreads();
  }
  float cb[8];
#pragma unroll
  for (int i = 0; i < 8; ++i) cb[i] = cst[db + ti * 8 + i];
  float* obase = out + (size_t)n * kCT * kL + (size_t)(db + ti * 8) * kL + tj * 8;
#pragma unroll
  for (int i = 0; i < 8; ++i) {
    float4 u = {acc[i][0] + cb[i], acc[i][1] + cb[i], acc[i][2] + cb[i],
                acc[i][3] + cb[i]};
    float4 v = {acc[i][4] + cb[i], acc[i][5] + cb[i], acc[i][6] + cb[i],
                acc[i][7] + cb[i]};
    *(float4*)(obase + (size_t)i * kL) = u;
    *(float4*)(obase + (size_t)i * kL + 4) = v;
  }
}

}  // namespace

extern "C" void kernel_launch(void* const* d_in, const int* in_sizes, int n_in,
                              void* d_out, int out_size, void* d_ws,
                              size_t ws_size, hipStream_t stream) {
  (void)in_sizes; (void)n_in; (void)out_size;
  const float* feat  = (const float*)d_in[0];
  const float* w_tc  = (const float*)d_in[1];
  const float* b_tc  = (const float*)d_in[2];
  const float* w_val = (const float*)d_in[3];
  const float* b_val = (const float*)d_in[4];
  const float* w_ds3 = (const float*)d_in[5];
  const float* b_ds3 = (const float*)d_in[6];
  const float* w_ds1 = (const float*)d_in[7];
  const float* b_ds1 = (const float*)d_in[8];
  const float* w_pos = (const float*)d_in[9];
  const float* b_pos = (const float*)d_in[10];
  const float* w_tok = (const float*)d_in[11];
  const float* b_tok = (const float*)d_in[12];
  float* out = (float*)d_out;

  float* ws = (float*)d_ws;
  size_t off = 0;
  float* tc = ws + off;   off += (size_t)kN * kHW * kL;    // 6,422,528
  float* bcat = ws + off; off += (size_t)kN * kKcat * kL;  // 1,179,648
  float* wcat = ws + off; off += (size_t)kCT * kKcat;      //   294,912
  float* cst = ws + off;  off += kCT;                      //       512
  int ksplit = 7;
  if (ws_size < (off + (size_t)7 * kN * kCT * kL) * sizeof(float)) ksplit = 1;
  float* part = ws + off;

  build_wcat_kernel<<<(kCT * kKcat + 255) / 256, 256, 0, stream>>>(w_tok, w_val, wcat);
  build_cst_kernel<<<2, 256, 0, stream>>>(w_tok, b_val, b_tok, cst);
  zero_pad_kernel<<<(kN * (kKcat - kTok) * kL + 255) / 256, 256, 0, stream>>>(bcat);
  tc_gemm_kernel<<<dim3(kHW / 64, kN), 64, 0, stream>>>(feat, w_tc, b_tc, tc);
  softmax_kernel<<<kN, 256, 0, stream>>>(tc);
  m_gemm_kernel<<<dim3(kCT / 64, kN, ksplit), 64, 0, stream>>>(feat, tc, part, kHW / ksplit);
  reduce_m_kernel<<<(kN * kCT * kL + 255) / 256, 256, 0, stream>>>(part, bcat, ksplit);
  pos_enc_kernel<<<kN, 64, 0, stream>>>(tc, w_ds3, b_ds3, w_ds1, b_ds1, w_pos, b_pos, bcat);
  out_gemm_kernel<<<dim3(kCT / 64, kN), 64, 0, stream>>>(wcat, bcat, cst, out);
}

// Round 2
// 582.468 us; speedup vs baseline: 1.4405x; 1.4405x over previous
//
#include <hip/hip_runtime.h>
#include <cstddef>

namespace {

constexpr int kN = 32;
constexpr int kC = 512;
constexpr int kHW = 3136;   // 56*56
constexpr int kL = 64;
constexpr int kCT = 512;
constexpr int kTok = 561;   // CT + 49
constexpr int kKcat = 576;  // 561 padded to 18*32
constexpr int kPC = 49;     // p-chunks of 64 rows (3136/64)

// ---------------- weight prep ----------------
__global__ __launch_bounds__(256) void build_wcat_kernel(
    const float* __restrict__ w_tok, const float* __restrict__ w_val,
    float* __restrict__ wcat) {
  int idx = blockIdx.x * 256 + threadIdx.x;
  if (idx >= kCT * kKcat) return;
  int d = idx / kKcat;
  int c = idx - d * kKcat;
  float v = 0.f;
  if (c < kCT) {
    int g = c >> 5, k = c & 31;
    const float* wt = w_tok + (size_t)d * kTok + g * 32;
    const float* wv = w_val + g * 1024 + k;
    float s = 0.f;
#pragma unroll
    for (int dp = 0; dp < 32; ++dp) s += wt[dp] * wv[dp * 32];
    v = s;
  } else if (c < kTok) {
    v = w_tok[(size_t)d * kTok + c];
  }
  wcat[idx] = v;
}

__global__ __launch_bounds__(256) void build_cst_kernel(
    const float* __restrict__ w_tok, const float* __restrict__ b_val,
    const float* __restrict__ b_tok, float* __restrict__ cst) {
  int d = blockIdx.x * 256 + threadIdx.x;
  if (d >= kCT) return;
  float s = b_tok[d];
  for (int c = 0; c < kCT; ++c) s += w_tok[(size_t)d * kTok + c] * b_val[c];
  cst[d] = s;
}

__global__ __launch_bounds__(256) void zero_pad_kernel(float* __restrict__ bcat) {
  int i = blockIdx.x * 256 + threadIdx.x;
  const int tot = kN * (kKcat - kTok) * kL;
  if (i >= tot) return;
  int n = i / ((kKcat - kTok) * kL);
  int r = i - n * ((kKcat - kTok) * kL);
  bcat[(size_t)n * kKcat * kL + (size_t)kTok * kL + r] = 0.f;
}

// ---------------- K1: tc_raw[n][p][l] = (w_tc @ feature[n] + b_tc)/sqrt(C) ----------------
__global__ __launch_bounds__(64) void tc_gemm_kernel(
    const float* __restrict__ feat, const float* __restrict__ w_tc,
    const float* __restrict__ b_tc, float* __restrict__ tc) {
  const int n = blockIdx.y;
  const int p0 = blockIdx.x * 64;
  const int tid = threadIdx.x;
  __shared__ float fs[32][64];   // [k][p]
  __shared__ float wsh[32][64];  // [k][l]
  const int tp = tid & 7;
  const int tl = tid >> 3;
  float acc[8][8];  // [l][p]
#pragma unroll
  for (int i = 0; i < 8; ++i)
#pragma unroll
    for (int j = 0; j < 8; ++j) acc[i][j] = 0.f;

  const float* fbase = feat + (size_t)n * kC * kHW + p0;
  const int col4 = (tid & 15) * 4;
  const int krow = tid >> 4;

  for (int c0 = 0; c0 < kC; c0 += 32) {
#pragma unroll
    for (int r = 0; r < 8; ++r) {
      int k = krow + r * 4;
      *(float4*)&fs[k][col4] =
          *(const float4*)(fbase + (size_t)(c0 + k) * kHW + col4);
    }
    const float* wrow = w_tc + (size_t)tid * kC + c0;
#pragma unroll
    for (int r = 0; r < 8; ++r) {
      float4 v = *(const float4*)(wrow + r * 4);
      wsh[r * 4 + 0][tid] = v.x;
      wsh[r * 4 + 1][tid] = v.y;
      wsh[r * 4 + 2][tid] = v.z;
      wsh[r * 4 + 3][tid] = v.w;
    }
    __syncthreads();
#pragma unroll 8
    for (int k = 0; k < 32; ++k) {
      float4 a0 = *(const float4*)&fs[k][tp * 8];
      float4 a1 = *(const float4*)&fs[k][tp * 8 + 4];
      float4 w0 = *(const float4*)&wsh[k][tl * 8];
      float4 w1 = *(const float4*)&wsh[k][tl * 8 + 4];
      float av[8] = {a0.x, a0.y, a0.z, a0.w, a1.x, a1.y, a1.z, a1.w};
      float wv[8] = {w0.x, w0.y, w0.z, w0.w, w1.x, w1.y, w1.z, w1.w};
#pragma unroll
      for (int i = 0; i < 8; ++i)
#pragma unroll
        for (int j = 0; j < 8; ++j) acc[i][j] += wv[i] * av[j];
    }
    __syncthreads();
  }
  const float inv = 0.04419417382415922f;  // 1/sqrt(512)
  float bt[8];
#pragma unroll
  for (int i = 0; i < 8; ++i) bt[i] = b_tc[tl * 8 + i];
  float* obase = tc + (size_t)n * kHW * kL + (size_t)(p0 + tp * 8) * kL + tl * 8;
#pragma unroll
  for (int j = 0; j < 8; ++j) {
    float4 u, v;
    u.x = (acc[0][j] + bt[0]) * inv;
    u.y = (acc[1][j] + bt[1]) * inv;
    u.z = (acc[2][j] + bt[2]) * inv;
    u.w = (acc[3][j] + bt[3]) * inv;
    v.x = (acc[4][j] + bt[4]) * inv;
    v.y = (acc[5][j] + bt[5]) * inv;
    v.z = (acc[6][j] + bt[6]) * inv;
    v.w = (acc[7][j] + bt[7]) * inv;
    *(float4*)(obase + (size_t)j * kL) = u;
    *(float4*)(obase + (size_t)j * kL + 4) = v;
  }
}

// ---------------- K2a: per-chunk softmax stats (max, sumexp) ----------------
// grid (n, 49 chunks), 256 threads; each block: 64 p-rows x 64 l; single read of tc
__global__ __launch_bounds__(256) void softmax_stats_kernel(
    const float* __restrict__ tc, float* __restrict__ pm, float* __restrict__ ps) {
  const int n = blockIdx.x, ch = blockIdx.y;
  const int tid = threadIdx.x, l = tid & 63, row = tid >> 6;
  const float* base = tc + (size_t)n * kHW * kL + (size_t)ch * 64 * kL + l;
  float x[16];
#pragma unroll
  for (int i = 0; i < 16; ++i) x[i] = base[(size_t)(row + i * 4) * kL];
  float m = x[0];
#pragma unroll
  for (int i = 1; i < 16; ++i) m = fmaxf(m, x[i]);
  float s = 0.f;
#pragma unroll
  for (int i = 0; i < 16; ++i) s += __expf(x[i] - m);
  __shared__ float sm[4][64], ss[4][64];
  sm[row][l] = m;
  ss[row][l] = s;
  __syncthreads();
  if (row == 0) {
    float m0 = sm[0][l], m1 = sm[1][l], m2 = sm[2][l], m3 = sm[3][l];
    float M = fmaxf(fmaxf(m0, m1), fmaxf(m2, m3));
    float S = ss[0][l] * __expf(m0 - M) + ss[1][l] * __expf(m1 - M) +
              ss[2][l] * __expf(m2 - M) + ss[3][l] * __expf(m3 - M);
    pm[((size_t)n * kPC + ch) * 64 + l] = M;
    ps[((size_t)n * kPC + ch) * 64 + l] = S;
  }
}

// ---------------- K2b: combine chunk stats -> per-(n,l) m, 1/sum ----------------
__global__ __launch_bounds__(64) void softmax_combine_kernel(
    const float* __restrict__ pm, const float* __restrict__ ps,
    float* __restrict__ mArr, float* __restrict__ invArr) {
  const int n = blockIdx.x, l = threadIdx.x;
  const float* pmB = pm + (size_t)n * kPC * 64 + l;
  const float* psB = ps + (size_t)n * kPC * 64 + l;
  float M = -3.0e38f;
  for (int c = 0; c < kPC; ++c) M = fmaxf(M, pmB[(size_t)c * 64]);
  float S = 0.f;
  for (int c = 0; c < kPC; ++c) S += psB[(size_t)c * 64] * __expf(pmB[(size_t)c * 64] - M);
  mArr[n * 64 + l] = M;
  invArr[n * 64 + l] = 1.f / S;
}

// ---------------- K3: partial[s][n][c][l] = feat @ softmax(tc) (norm fused) ----------------
__global__ __launch_bounds__(64) void m_gemm_kernel(
    const float* __restrict__ feat, const float* __restrict__ tc,
    const float* __restrict__ mArr, const float* __restrict__ invArr,
    float* __restrict__ part, int klen) {
  const int cb = blockIdx.x * 64;
  const int n = blockIdx.y;
  const int s = blockIdx.z;
  const int k0 = s * klen;
  const int tid = threadIdx.x;
  __shared__ float ash[32][64];  // [k][c]
  __shared__ float bsh[32][64];  // [k][l]
  const int ti = tid >> 3;  // c
  const int tj = tid & 7;   // l
  float acc[8][8];
#pragma unroll
  for (int i = 0; i < 8; ++i)
#pragma unroll
    for (int j = 0; j < 8; ++j) acc[i][j] = 0.f;

  const float* fbase = feat + (size_t)n * kC * kHW + (size_t)cb * kHW + k0;
  const float* bbase = tc + (size_t)n * kHW * kL + (size_t)k0 * kL;
  const int col4 = (tid & 15) * 4;
  const int krow = tid >> 4;
  const float m0 = mArr[n * 64 + col4 + 0], i0 = invArr[n * 64 + col4 + 0];
  const float m1 = mArr[n * 64 + col4 + 1], i1 = invArr[n * 64 + col4 + 1];
  const float m2 = mArr[n * 64 + col4 + 2], i2 = invArr[n * 64 + col4 + 2];
  const float m3 = mArr[n * 64 + col4 + 3], i3 = invArr[n * 64 + col4 + 3];

  for (int kk = 0; kk < klen; kk += 32) {
    const float* frow = fbase + (size_t)tid * kHW + kk;
#pragma unroll
    for (int r = 0; r < 8; ++r) {
      float4 v = *(const float4*)(frow + r * 4);
      ash[r * 4 + 0][tid] = v.x;
      ash[r * 4 + 1][tid] = v.y;
      ash[r * 4 + 2][tid] = v.z;
      ash[r * 4 + 3][tid] = v.w;
    }
#pragma unroll
    for (int r = 0; r < 8; ++r) {
      int k = krow + r * 4;
      float4 v = *(const float4*)(bbase + (size_t)(kk + k) * kL + col4);
      v.x = __expf(v.x - m0) * i0;
      v.y = __expf(v.y - m1) * i1;
      v.z = __expf(v.z - m2) * i2;
      v.w = __expf(v.w - m3) * i3;
      *(float4*)&bsh[k][col4] = v;
    }
    __syncthreads();
#pragma unroll 8
    for (int k = 0; k < 32; ++k) {
      float4 a0 = *(const float4*)&ash[k][ti * 8];
      float4 a1 = *(const float4*)&ash[k][ti * 8 + 4];
      float4 b0 = *(const float4*)&bsh[k][tj * 8];
      float4 b1 = *(const float4*)&bsh[k][tj * 8 + 4];
      float av[8] = {a0.x, a0.y, a0.z, a0.w, a1.x, a1.y, a1.z, a1.w};
      float bv[8] = {b0.x, b0.y, b0.z, b0.w, b1.x, b1.y, b1.z, b1.w};
#pragma unroll
      for (int i = 0; i < 8; ++i)
#pragma unroll
        for (int j = 0; j < 8; ++j) acc[i][j] += av[i] * bv[j];
    }
    __syncthreads();
  }
  float* obase = part + ((size_t)s * kN + n) * kCT * kL +
                 (size_t)(cb + ti * 8) * kL + tj * 8;
#pragma unroll
  for (int i = 0; i < 8; ++i) {
    float4 u = {acc[i][0], acc[i][1], acc[i][2], acc[i][3]};
    float4 v = {acc[i][4], acc[i][5], acc[i][6], acc[i][7]};
    *(float4*)(obase + (size_t)i * kL) = u;
    *(float4*)(obase + (size_t)i * kL + 4) = v;
  }
}

__global__ __launch_bounds__(256) void reduce_m_kernel(
    const float* __restrict__ part, float* __restrict__ bcat, int ksplit) {
  int i = blockIdx.x * 256 + threadIdx.x;
  if (i >= kN * kCT * kL) return;
  int n = i >> 15;
  int r = i & 32767;
  float s = 0.f;
  for (int ss = 0; ss < ksplit; ++ss)
    s += part[(size_t)ss * kN * kCT * kL + i];
  bcat[(size_t)n * kKcat * kL + r] = s;
}

// ---------------- K4a: PosEncoder conv (one output pixel per thread) ----------------
// pc image m = n*64+lp is the reinterpreted (p,l)-block: flat f = lp*3136 + 224*i + 4*j
// softmax channel of a tap = f & 63, p-row = f >> 6 (lp*3136 is a multiple of 64).
__global__ __launch_bounds__(256) void pos_conv_kernel(
    const float* __restrict__ tc, const float* __restrict__ mArr,
    const float* __restrict__ invArr, const float* __restrict__ w3,
    const float* __restrict__ b3, const float* __restrict__ w1,
    const float* __restrict__ b1, float* __restrict__ pcl) {
  int idx = blockIdx.x * 256 + threadIdx.x;
  if (idx >= kN * kL * 49) return;
  int n = idx / (kL * 49);
  int r = idx - n * (kL * 49);
  int lp = r / 49;
  int o = r - lp * 49;
  int y = o / 7, x = o - y * 7;
  const float* base = tc + (size_t)n * kHW * kL + (size_t)lp * kHW;
  const float* mB = mArr + n * 64;
  const float* iB = invArr + n * 64;
  float a = 0.f;
#pragma unroll
  for (int dy = 0; dy < 3; ++dy) {
    int i = 2 * y - 1 + dy;
    if (i < 0 || i >= 14) continue;
#pragma unroll
    for (int dx = 0; dx < 3; ++dx) {
      int j = 2 * x - 1 + dx;
      if (j < 0 || j >= 14) continue;
      int t = 224 * i + 4 * j;
      float raw = base[t];
      int lsm = t & 63;
      a += w3[dy * 3 + dx] * (__expf(raw - mB[lsm]) * iB[lsm]);
    }
  }
  pcl[idx] = (a + b3[0]) * w1[0] + b1[0];
}

// ---------------- K4b: pos = w_pos @ pc + b_pos -> bcat rows 512..560 ----------------
__global__ __launch_bounds__(256) void pos_out_kernel(
    const float* __restrict__ pcl, const float* __restrict__ wp,
    const float* __restrict__ bp, float* __restrict__ bcat) {
  const int n = blockIdx.x;
  __shared__ float t[64 * 49];
  for (int i = threadIdx.x; i < 64 * 49; i += 256)
    t[i] = pcl[(size_t)n * 64 * 49 + i];
  __syncthreads();
  for (int o = threadIdx.x; o < 49 * 64; o += 256) {
    int d = o >> 6, l = o & 63;
    float s = bp[d];
#pragma unroll 7
    for (int q = 0; q < 49; ++q) s += wp[d * 49 + q] * t[l * 49 + q];
    bcat[(size_t)n * kKcat * kL + (size_t)(kCT + d) * kL + l] = s;
  }
}

// ---------------- K5: out[n][d][l] = cst[d] + wcat[d,:] @ bcat[n][:,l] ----------------
__global__ __launch_bounds__(64) void out_gemm_kernel(
    const float* __restrict__ wcat, const float* __restrict__ bcat,
    const float* __restrict__ cst, float* __restrict__ out) {
  const int db = blockIdx.x * 64;
  const int n = blockIdx.y;
  const int tid = threadIdx.x;
  __shared__ float ash[32][64];  // [k][d]
  __shared__ float bsh[32][64];  // [k][l]
  const int ti = tid >> 3;  // d
  const int tj = tid & 7;   // l
  float acc[8][8];
#pragma unroll
  for (int i = 0; i < 8; ++i)
#pragma unroll
    for (int j = 0; j < 8; ++j) acc[i][j] = 0.f;

  const float* arow = wcat + (size_t)(db + tid) * kKcat;
  const float* bbase = bcat + (size_t)n * kKcat * kL;
  const int col4 = (tid & 15) * 4;
  const int krow = tid >> 4;

  for (int c0 = 0; c0 < kKcat; c0 += 32) {
#pragma unroll
    for (int r = 0; r < 8; ++r) {
      float4 v = *(const float4*)(arow + c0 + r * 4);
      ash[r * 4 + 0][tid] = v.x;
      ash[r * 4 + 1][tid] = v.y;
      ash[r * 4 + 2][tid] = v.z;
      ash[r * 4 + 3][tid] = v.w;
    }
#pragma unroll
    for (int r = 0; r < 8; ++r) {
      int k = krow + r * 4;
      *(float4*)&bsh[k][col4] =
          *(const float4*)(bbase + (size_t)(c0 + k) * kL + col4);
    }
    __syncthreads();
#pragma unroll 8
    for (int k = 0; k < 32; ++k) {
      float4 a0 = *(const float4*)&ash[k][ti * 8];
      float4 a1 = *(const float4*)&ash[k][ti * 8 + 4];
      float4 b0 = *(const float4*)&bsh[k][tj * 8];
      float4 b1 = *(const float4*)&bsh[k][tj * 8 + 4];
      float av[8] = {a0.x, a0.y, a0.z, a0.w, a1.x, a1.y, a1.z, a1.w};
      float bv[8] = {b0.x, b0.y, b0.z, b0.w, b1.x, b1.y, b1.z, b1.w};
#pragma unroll
      for (int i = 0; i < 8; ++i)
#pragma unroll
        for (int j = 0; j < 8; ++j) acc[i][j] += av[i] * bv[j];
    }
    __syncthreads();
  }
  float cb[8];
#pragma unroll
  for (int i = 0; i < 8; ++i) cb[i] = cst[db + ti * 8 + i];
  float* obase = out + (size_t)n * kCT * kL + (size_t)(db + ti * 8) * kL + tj * 8;
#pragma unroll
  for (int i = 0; i < 8; ++i) {
    float4 u = {acc[i][0] + cb[i], acc[i][1] + cb[i], acc[i][2] + cb[i],
                acc[i][3] + cb[i]};
    float4 v = {acc[i][4] + cb[i], acc[i][5] + cb[i], acc[i][6] + cb[i],
                acc[i][7] + cb[i]};
    *(float4*)(obase + (size_t)i * kL) = u;
    *(float4*)(obase + (size_t)i * kL + 4) = v;
  }
}

}  // namespace

extern "C" void kernel_launch(void* const* d_in, const int* in_sizes, int n_in,
                              void* d_out, int out_size, void* d_ws,
                              size_t ws_size, hipStream_t stream) {
  (void)in_sizes; (void)n_in; (void)out_size;
  const float* feat  = (const float*)d_in[0];
  const float* w_tc  = (const float*)d_in[1];
  const float* b_tc  = (const float*)d_in[2];
  const float* w_val = (const float*)d_in[3];
  const float* b_val = (const float*)d_in[4];
  const float* w_ds3 = (const float*)d_in[5];
  const float* b_ds3 = (const float*)d_in[6];
  const float* w_ds1 = (const float*)d_in[7];
  const float* b_ds1 = (const float*)d_in[8];
  const float* w_pos = (const float*)d_in[9];
  const float* b_pos = (const float*)d_in[10];
  const float* w_tok = (const float*)d_in[11];
  const float* b_tok = (const float*)d_in[12];
  float* out = (float*)d_out;

  float* ws = (float*)d_ws;
  size_t off = 0;
  float* tc = ws + off;     off += (size_t)kN * kHW * kL;    // 6,422,528
  float* bcat = ws + off;   off += (size_t)kN * kKcat * kL;  // 1,179,648
  float* wcat = ws + off;   off += (size_t)kCT * kKcat;      //   294,912
  float* cst = ws + off;    off += kCT;                      //       512
  float* pm = ws + off;     off += (size_t)kN * kPC * 64;    //   100,352
  float* ps = ws + off;     off += (size_t)kN * kPC * 64;    //   100,352
  float* mArr = ws + off;   off += kN * 64;                  //     2,048
  float* invArr = ws + off; off += kN * 64;                  //     2,048
  float* pcl = ws + off;    off += (size_t)kN * kL * 49;     //   100,352
  int ksplit = 7;
  if (ws_size < (off + (size_t)7 * kN * kCT * kL) * sizeof(float)) ksplit = 1;
  float* part = ws + off;

  build_wcat_kernel<<<(kCT * kKcat + 255) / 256, 256, 0, stream>>>(w_tok, w_val, wcat);
  build_cst_kernel<<<2, 256, 0, stream>>>(w_tok, b_val, b_tok, cst);
  zero_pad_kernel<<<(kN * (kKcat - kTok) * kL + 255) / 256, 256, 0, stream>>>(bcat);
  tc_gemm_kernel<<<dim3(kHW / 64, kN), 64, 0, stream>>>(feat, w_tc, b_tc, tc);
  softmax_stats_kernel<<<dim3(kN, kPC), 256, 0, stream>>>(tc, pm, ps);
  softmax_combine_kernel<<<kN, 64, 0, stream>>>(pm, ps, mArr, invArr);
  m_gemm_kernel<<<dim3(kCT / 64, kN, ksplit), 64, 0, stream>>>(
      feat, tc, mArr, invArr, part, kHW / ksplit);
  reduce_m_kernel<<<(kN * kCT * kL + 255) / 256, 256, 0, stream>>>(part, bcat, ksplit);
  pos_conv_kernel<<<(kN * kL * 49 + 255) / 256, 256, 0, stream>>>(
      tc, mArr, invArr, w_ds3, b_ds3, w_ds1, b_ds1, pcl);
  pos_out_kernel<<<kN, 256, 0, stream>>>(pcl, w_pos, b_pos, bcat);
  out_gemm_kernel<<<dim3(kCT / 64, kN), 64, 0, stream>>>(wcat, bcat, cst, out);
}

// Round 3
// 448.065 us; speedup vs baseline: 1.8727x; 1.3000x over previous
//
#include <hip/hip_runtime.h>
#include <cstddef>
#include <cstdint>

namespace {

constexpr int kN = 32;
constexpr int kC = 512;
constexpr int kHW = 3136;   // 56*56
constexpr int kL = 64;
constexpr int kCT = 512;
constexpr int kTok = 561;   // CT + 49
constexpr int kKcat = 576;  // 561 padded to 18*32

typedef float fx4 __attribute__((ext_vector_type(4)));
typedef float f32x4 __attribute__((ext_vector_type(4)));
typedef short short8 __attribute__((ext_vector_type(8)));
typedef unsigned int u32x2 __attribute__((ext_vector_type(2)));

// round-half-up f32->bf16, pack two into one u32 (low = a, high = b)
static __device__ inline unsigned pack_bf16(float a, float b) {
  unsigned ua = __builtin_bit_cast(unsigned, a) + 0x8000u;
  unsigned ub = __builtin_bit_cast(unsigned, b) + 0x8000u;
  return __builtin_amdgcn_perm(ub, ua, 0x07060302u);
}

// ---------------- weight prep ----------------
__global__ __launch_bounds__(256) void build_wcat_kernel(
    const float* __restrict__ w_tok, const float* __restrict__ w_val,
    float* __restrict__ wcat) {
  int idx = blockIdx.x * 256 + threadIdx.x;
  if (idx >= kCT * kKcat) return;
  int d = idx / kKcat;
  int c = idx - d * kKcat;
  float v = 0.f;
  if (c < kCT) {
    int g = c >> 5, k = c & 31;
    const float* wt = w_tok + (size_t)d * kTok + g * 32;
    const float* wv = w_val + g * 1024 + k;
    float s = 0.f;
#pragma unroll
    for (int dp = 0; dp < 32; ++dp) s += wt[dp] * wv[dp * 32];
    v = s;
  } else if (c < kTok) {
    v = w_tok[(size_t)d * kTok + c];
  }
  wcat[idx] = v;
}

__global__ __launch_bounds__(256) void build_cst_kernel(
    const float* __restrict__ w_tok, const float* __restrict__ b_val,
    const float* __restrict__ b_tok, float* __restrict__ cst) {
  int d = blockIdx.x * 256 + threadIdx.x;
  if (d >= kCT) return;
  float s = b_tok[d];
  for (int c = 0; c < kCT; ++c) s += w_tok[(size_t)d * kTok + c] * b_val[c];
  cst[d] = s;
}

// zero bcat pad columns 561..575 (bcat layout [n][l][kKcat])
__global__ __launch_bounds__(256) void zero_pad_kernel(float* __restrict__ bcat) {
  int i = blockIdx.x * 256 + threadIdx.x;
  const int tot = kN * kL * (kKcat - kTok);
  if (i >= tot) return;
  int n = i / (kL * 15);
  int r = i - n * (kL * 15);
  int l = r / 15;
  int k = kTok + (r - l * 15);
  bcat[(size_t)n * kL * kKcat + (size_t)l * kKcat + k] = 0.f;
}

// ---------------- K1: tcT[n][l][p] = (w_tc @ feat + b_tc)/sqrt(C), bf16 MFMA ----------------
// block 256 thr (4 waves), tile 64 l x 256 p, BK=64 c; grid (13, N). p clamped.
__global__ __launch_bounds__(256) void tc_gemm_kernel(
    const float* __restrict__ feat, const float* __restrict__ w_tc,
    const float* __restrict__ b_tc, float* __restrict__ tcT) {
  const int n = blockIdx.y;
  const int pb = blockIdx.x * 256;
  const int tid = threadIdx.x;
  const int wave = tid >> 6, lane = tid & 63;
  const int quad = lane >> 4, l16 = lane & 15;
  __shared__ unsigned short As[64][72];
  __shared__ unsigned short Bs[256][72];
  __shared__ float bsm[64];
  if (tid < 64) bsm[tid] = b_tc[tid];

  f32x4 acc[4][4];
#pragma unroll
  for (int i = 0; i < 4; ++i)
#pragma unroll
    for (int j = 0; j < 4; ++j) acc[i][j] = (f32x4){0.f, 0.f, 0.f, 0.f};

  const float* fb = feat + (size_t)n * kC * kHW;
  const int al = tid & 63, akg = (tid >> 6) * 16;
  const int bc4 = (tid & 15) * 4, bpl0 = (tid >> 4) * 4;

  for (int c0 = 0; c0 < kC; c0 += 64) {
    // stage A = w_tc rows [l][c]
    const float* asrc = w_tc + (size_t)al * kC + c0 + akg;
#pragma unroll
    for (int u = 0; u < 4; ++u) {
      fx4 v = *(const fx4*)(asrc + u * 4);
      u32x2 w = {pack_bf16(v[0], v[1]), pack_bf16(v[2], v[3])};
      *(u32x2*)&As[al][akg + u * 4] = w;
    }
    // stage B = feature^T tile: Bs[p][c], transpose 4x4 in regs
#pragma unroll
    for (int pass = 0; pass < 4; ++pass) {
      int pl = bpl0 + pass * 64;
      int pe = pb + pl;
      pe = pe < 3132 ? pe : 3132;
      fx4 v0 = *(const fx4*)(fb + (size_t)(c0 + bc4 + 0) * kHW + pe);
      fx4 v1 = *(const fx4*)(fb + (size_t)(c0 + bc4 + 1) * kHW + pe);
      fx4 v2 = *(const fx4*)(fb + (size_t)(c0 + bc4 + 2) * kHW + pe);
      fx4 v3 = *(const fx4*)(fb + (size_t)(c0 + bc4 + 3) * kHW + pe);
#pragma unroll
      for (int j = 0; j < 4; ++j) {
        u32x2 w = {pack_bf16(v0[j], v1[j]), pack_bf16(v2[j], v3[j])};
        *(u32x2*)&Bs[pl + j][bc4] = w;
      }
    }
    __syncthreads();
#pragma unroll
    for (int ks = 0; ks < 2; ++ks) {
      short8 a[4], b[4];
#pragma unroll
      for (int i = 0; i < 4; ++i)
        a[i] = *(const short8*)&As[i * 16 + l16][ks * 32 + quad * 8];
#pragma unroll
      for (int j = 0; j < 4; ++j)
        b[j] = *(const short8*)&Bs[wave * 64 + j * 16 + l16][ks * 32 + quad * 8];
#pragma unroll
      for (int i = 0; i < 4; ++i)
#pragma unroll
        for (int j = 0; j < 4; ++j)
          acc[i][j] = __builtin_amdgcn_mfma_f32_16x16x32_bf16(a[i], b[j], acc[i][j], 0, 0, 0);
    }
    __syncthreads();
  }

  const float inv = 0.04419417382415922f;  // 1/sqrt(512)
  float* ob = tcT + (size_t)n * kL * kHW;
#pragma unroll
  for (int ti = 0; ti < 4; ++ti) {
#pragma unroll
    for (int tj = 0; tj < 4; ++tj) {
      int pg = pb + wave * 64 + tj * 16 + l16;
      if (pg < kHW) {
#pragma unroll
        for (int r = 0; r < 4; ++r) {
          int l = ti * 16 + quad * 4 + r;
          ob[(size_t)l * kHW + pg] = (acc[ti][tj][r] + bsm[l]) * inv;
        }
      }
    }
  }
}

// ---------------- K2: softmax stats, one wave per (n,l) row ----------------
__global__ __launch_bounds__(256) void softmax_stats_kernel(
    const float* __restrict__ tcT, float* __restrict__ mArr,
    float* __restrict__ invArr) {
  const int row = blockIdx.x * 4 + (threadIdx.x >> 6);
  const int lane = threadIdx.x & 63;
  const float* src = tcT + (size_t)row * kHW + lane * 4;
  fx4 x[13];
#pragma unroll
  for (int i = 0; i < 12; ++i) x[i] = *(const fx4*)(src + i * 256);
  if (lane < 16)
    x[12] = *(const fx4*)(src + 3072);
  else
    x[12] = (fx4){-1e30f, -1e30f, -1e30f, -1e30f};
  float m = -1e30f;
#pragma unroll
  for (int i = 0; i < 13; ++i)
    m = fmaxf(m, fmaxf(fmaxf(x[i][0], x[i][1]), fmaxf(x[i][2], x[i][3])));
#pragma unroll
  for (int off = 32; off >= 1; off >>= 1) m = fmaxf(m, __shfl_xor(m, off));
  float s = 0.f;
#pragma unroll
  for (int i = 0; i < 13; ++i) {
    s += __expf(x[i][0] - m) + __expf(x[i][1] - m) + __expf(x[i][2] - m) +
         __expf(x[i][3] - m);
  }
#pragma unroll
  for (int off = 32; off >= 1; off >>= 1) s += __shfl_xor(s, off);
  if (lane == 0) {
    mArr[row] = m;
    invArr[row] = 1.f / s;
  }
}

// ---------------- K3: part[s][n][l][c] = softmax(tcT) @ feat^T, bf16 MFMA ----------------
// block 256 thr, tile 64 l x 256 c, BK=64 p; grid (2, N, ksplit)
__global__ __launch_bounds__(256) void m_gemm_kernel(
    const float* __restrict__ feat, const float* __restrict__ tcT,
    const float* __restrict__ mArr, const float* __restrict__ invArr,
    float* __restrict__ part, int klen) {
  const int cb = blockIdx.x * 256;
  const int n = blockIdx.y;
  const int s = blockIdx.z;
  const int p0s = s * klen;
  const int tid = threadIdx.x;
  const int wave = tid >> 6, lane = tid & 63;
  const int quad = lane >> 4, l16 = lane & 15;
  __shared__ unsigned short As[64][72];
  __shared__ unsigned short Bs[256][72];

  const int al = tid & 63, akg = (tid >> 6) * 16;
  const float sm = mArr[n * 64 + al];
  const float si = invArr[n * 64 + al];

  f32x4 acc[4][4];
#pragma unroll
  for (int i = 0; i < 4; ++i)
#pragma unroll
    for (int j = 0; j < 4; ++j) acc[i][j] = (f32x4){0.f, 0.f, 0.f, 0.f};

  const float* tb = tcT + (size_t)(n * 64 + al) * kHW;
  const float* fb = feat + (size_t)n * kC * kHW;
  const int bkg = (tid >> 6) * 16, bcr = tid & 63;

  for (int p0 = p0s; p0 < p0s + klen; p0 += 64) {
    // stage A = exp-normalized tcT rows [l][p]
#pragma unroll
    for (int u = 0; u < 4; ++u) {
      fx4 v = *(const fx4*)(tb + p0 + akg + u * 4);
      float e0 = __expf(v[0] - sm) * si;
      float e1 = __expf(v[1] - sm) * si;
      float e2 = __expf(v[2] - sm) * si;
      float e3 = __expf(v[3] - sm) * si;
      u32x2 w = {pack_bf16(e0, e1), pack_bf16(e2, e3)};
      *(u32x2*)&As[al][akg + u * 4] = w;
    }
    // stage B = feature rows [c][p] (native)
#pragma unroll
    for (int pass = 0; pass < 4; ++pass) {
      int c = cb + pass * 64 + bcr;
      const float* src = fb + (size_t)c * kHW + p0 + bkg;
#pragma unroll
      for (int u = 0; u < 4; ++u) {
        fx4 v = *(const fx4*)(src + u * 4);
        u32x2 w = {pack_bf16(v[0], v[1]), pack_bf16(v[2], v[3])};
        *(u32x2*)&Bs[pass * 64 + bcr][bkg + u * 4] = w;
      }
    }
    __syncthreads();
#pragma unroll
    for (int ks = 0; ks < 2; ++ks) {
      short8 a[4], b[4];
#pragma unroll
      for (int i = 0; i < 4; ++i)
        a[i] = *(const short8*)&As[i * 16 + l16][ks * 32 + quad * 8];
#pragma unroll
      for (int j = 0; j < 4; ++j)
        b[j] = *(const short8*)&Bs[wave * 64 + j * 16 + l16][ks * 32 + quad * 8];
#pragma unroll
      for (int i = 0; i < 4; ++i)
#pragma unroll
        for (int j = 0; j < 4; ++j)
          acc[i][j] = __builtin_amdgcn_mfma_f32_16x16x32_bf16(a[i], b[j], acc[i][j], 0, 0, 0);
    }
    __syncthreads();
  }

  float* ob = part + (size_t)(s * kN + n) * kL * kCT;
#pragma unroll
  for (int ti = 0; ti < 4; ++ti) {
#pragma unroll
    for (int tj = 0; tj < 4; ++tj) {
      int cg = cb + wave * 64 + tj * 16 + l16;
#pragma unroll
      for (int r = 0; r < 4; ++r) {
        int l = ti * 16 + quad * 4 + r;
        ob[(size_t)l * kCT + cg] = acc[ti][tj][r];
      }
    }
  }
}

// ---------------- reduce: bcat[n][l][c] = sum_s part[s][n][l][c] ----------------
__global__ __launch_bounds__(256) void reduce_m_kernel(
    const float* __restrict__ part, float* __restrict__ bcat, int ksplit) {
  int i = blockIdx.x * 256 + threadIdx.x;
  if (i >= kN * kL * kCT) return;
  int n = i >> 15;
  int r = i & 32767;
  int l = r >> 9;
  int c = r & 511;
  float s = 0.f;
  for (int ss = 0; ss < ksplit; ++ss)
    s += part[(size_t)ss * kN * kL * kCT + i];
  bcat[(size_t)n * kL * kKcat + (size_t)l * kKcat + c] = s;
}

// ---------------- K4a: PosEncoder conv ----------------
__global__ __launch_bounds__(256) void pos_conv_kernel(
    const float* __restrict__ tcT, const float* __restrict__ mArr,
    const float* __restrict__ invArr, const float* __restrict__ w3,
    const float* __restrict__ b3, const float* __restrict__ w1,
    const float* __restrict__ b1, float* __restrict__ pcl) {
  int idx = blockIdx.x * 256 + threadIdx.x;
  if (idx >= kN * kL * 49) return;
  int n = idx / (kL * 49);
  int r = idx - n * (kL * 49);
  int lp = r / 49;
  int o = r - lp * 49;
  int y = o / 7, x = o - y * 7;
  const float* tb = tcT + (size_t)n * kL * kHW;
  const float* mB = mArr + n * 64;
  const float* iB = invArr + n * 64;
  float a = 0.f;
#pragma unroll
  for (int dy = 0; dy < 3; ++dy) {
    int i = 2 * y - 1 + dy;
    if (i < 0 || i >= 14) continue;
#pragma unroll
    for (int dx = 0; dx < 3; ++dx) {
      int j = 2 * x - 1 + dx;
      if (j < 0 || j >= 14) continue;
      int t = 224 * i + 4 * j;          // flat offset within image block
      int lsm = t & 63;                  // softmax channel
      int p = lp * 49 + (t >> 6);        // p-row in tcT
      float raw = tb[(size_t)lsm * kHW + p];
      a += w3[dy * 3 + dx] * (__expf(raw - mB[lsm]) * iB[lsm]);
    }
  }
  pcl[idx] = (a + b3[0]) * w1[0] + b1[0];
}

// ---------------- K4b: pos -> bcat[n][l][512+d] ----------------
__global__ __launch_bounds__(256) void pos_out_kernel(
    const float* __restrict__ pcl, const float* __restrict__ wp,
    const float* __restrict__ bp, float* __restrict__ bcat) {
  const int n = blockIdx.x;
  __shared__ float t[64 * 49];
  for (int i = threadIdx.x; i < 64 * 49; i += 256)
    t[i] = pcl[(size_t)n * 64 * 49 + i];
  __syncthreads();
  for (int o = threadIdx.x; o < 64 * 49; o += 256) {
    int l = o / 49, d = o - l * 49;
    float s = bp[d];
#pragma unroll 7
    for (int q = 0; q < 49; ++q) s += wp[d * 49 + q] * t[l * 49 + q];
    bcat[(size_t)n * kL * kKcat + (size_t)l * kKcat + kCT + d] = s;
  }
}

// ---------------- K5: out[n][d][l] = cst[d] + wcat[d,:] @ bcat[n][l,:], bf16 MFMA ----------------
// block 256 thr, tile 128 d x 64 l, BK=64; grid (4, N)
__global__ __launch_bounds__(256) void out_gemm_kernel(
    const float* __restrict__ wcat, const float* __restrict__ bcat,
    const float* __restrict__ cst, float* __restrict__ out) {
  const int db = blockIdx.x * 128;
  const int n = blockIdx.y;
  const int tid = threadIdx.x;
  const int wave = tid >> 6, lane = tid & 63;
  const int quad = lane >> 4, l16 = lane & 15;
  __shared__ unsigned short As[128][72];
  __shared__ unsigned short Bs[64][72];
  __shared__ float csm[128];
  if (tid < 128) csm[tid] = cst[db + tid];

  f32x4 acc[2][4];
#pragma unroll
  for (int i = 0; i < 2; ++i)
#pragma unroll
    for (int j = 0; j < 4; ++j) acc[i][j] = (f32x4){0.f, 0.f, 0.f, 0.f};

  const int ad = tid & 127, akg = (tid >> 7) * 32;
  const int bl = tid & 63, bkg = (tid >> 6) * 16;
  const float* ab = wcat + (size_t)(db + ad) * kKcat + akg;
  const float* bb = bcat + (size_t)n * kL * kKcat + (size_t)bl * kKcat + bkg;

  for (int k0 = 0; k0 < kKcat; k0 += 64) {
#pragma unroll
    for (int u = 0; u < 8; ++u) {
      fx4 v = *(const fx4*)(ab + k0 + u * 4);
      u32x2 w = {pack_bf16(v[0], v[1]), pack_bf16(v[2], v[3])};
      *(u32x2*)&As[ad][akg + u * 4] = w;
    }
#pragma unroll
    for (int u = 0; u < 4; ++u) {
      fx4 v = *(const fx4*)(bb + k0 + u * 4);
      u32x2 w = {pack_bf16(v[0], v[1]), pack_bf16(v[2], v[3])};
      *(u32x2*)&Bs[bl][bkg + u * 4] = w;
    }
    __syncthreads();
#pragma unroll
    for (int ks = 0; ks < 2; ++ks) {
      short8 a[2], b[4];
#pragma unroll
      for (int i = 0; i < 2; ++i)
        a[i] = *(const short8*)&As[wave * 32 + i * 16 + l16][ks * 32 + quad * 8];
#pragma unroll
      for (int j = 0; j < 4; ++j)
        b[j] = *(const short8*)&Bs[j * 16 + l16][ks * 32 + quad * 8];
#pragma unroll
      for (int i = 0; i < 2; ++i)
#pragma unroll
        for (int j = 0; j < 4; ++j)
          acc[i][j] = __builtin_amdgcn_mfma_f32_16x16x32_bf16(a[i], b[j], acc[i][j], 0, 0, 0);
    }
    __syncthreads();
  }

  float* ob = out + (size_t)n * kCT * kL;
#pragma unroll
  for (int ti = 0; ti < 2; ++ti) {
#pragma unroll
    for (int tj = 0; tj < 4; ++tj) {
      int lg = tj * 16 + l16;
#pragma unroll
      for (int r = 0; r < 4; ++r) {
        int dl = wave * 32 + ti * 16 + quad * 4 + r;
        ob[(size_t)(db + dl) * kL + lg] = acc[ti][tj][r] + csm[dl];
      }
    }
  }
}

}  // namespace

extern "C" void kernel_launch(void* const* d_in, const int* in_sizes, int n_in,
                              void* d_out, int out_size, void* d_ws,
                              size_t ws_size, hipStream_t stream) {
  (void)in_sizes; (void)n_in; (void)out_size;
  const float* feat  = (const float*)d_in[0];
  const float* w_tc  = (const float*)d_in[1];
  const float* b_tc  = (const float*)d_in[2];
  const float* w_val = (const float*)d_in[3];
  const float* b_val = (const float*)d_in[4];
  const float* w_ds3 = (const float*)d_in[5];
  const float* b_ds3 = (const float*)d_in[6];
  const float* w_ds1 = (const float*)d_in[7];
  const float* b_ds1 = (const float*)d_in[8];
  const float* w_pos = (const float*)d_in[9];
  const float* b_pos = (const float*)d_in[10];
  const float* w_tok = (const float*)d_in[11];
  const float* b_tok = (const float*)d_in[12];
  float* out = (float*)d_out;

  float* ws = (float*)d_ws;
  size_t off = 0;
  float* tcT = ws + off;    off += (size_t)kN * kL * kHW;    // 6,422,528
  float* bcat = ws + off;   off += (size_t)kN * kL * kKcat;  // 1,179,648
  float* wcat = ws + off;   off += (size_t)kCT * kKcat;      //   294,912
  float* cst = ws + off;    off += kCT;
  float* mArr = ws + off;   off += kN * 64;
  float* invArr = ws + off; off += kN * 64;
  float* pcl = ws + off;    off += (size_t)kN * kL * 49;
  int ksplit = 7;
  if (ws_size < (off + (size_t)7 * kN * kL * kCT) * sizeof(float)) ksplit = 1;
  float* part = ws + off;

  build_wcat_kernel<<<(kCT * kKcat + 255) / 256, 256, 0, stream>>>(w_tok, w_val, wcat);
  build_cst_kernel<<<2, 256, 0, stream>>>(w_tok, b_val, b_tok, cst);
  zero_pad_kernel<<<(kN * kL * 15 + 255) / 256, 256, 0, stream>>>(bcat);
  tc_gemm_kernel<<<dim3(13, kN), 256, 0, stream>>>(feat, w_tc, b_tc, tcT);
  softmax_stats_kernel<<<kN * kL / 4, 256, 0, stream>>>(tcT, mArr, invArr);
  m_gemm_kernel<<<dim3(2, kN, ksplit), 256, 0, stream>>>(
      feat, tcT, mArr, invArr, part, kHW / ksplit);
  reduce_m_kernel<<<(kN * kL * kCT + 255) / 256, 256, 0, stream>>>(part, bcat, ksplit);
  pos_conv_kernel<<<(kN * kL * 49 + 255) / 256, 256, 0, stream>>>(
      tcT, mArr, invArr, w_ds3, b_ds3, w_ds1, b_ds1, pcl);
  pos_out_kernel<<<kN, 256, 0, stream>>>(pcl, w_pos, b_pos, bcat);
  out_gemm_kernel<<<dim3(4, kN), 256, 0, stream>>>(wcat, bcat, cst, out);
}